// Round 1
// baseline (874.079 us; speedup 1.0000x reference)
//
#include <hip/hip_runtime.h>
#include <hip/hip_bf16.h>

typedef short bf16x8 __attribute__((ext_vector_type(8)));
typedef float f32x4 __attribute__((ext_vector_type(4)));
typedef unsigned short u16;

#define NTOK 2048
#define CDIM 2048
#define TSEQ 1024
#define NH   32
#define NKV  8
#define DH   128
#define NE   8
#define FDIM 768
#define CAP  2048

__device__ __forceinline__ u16 f2bf(float f){
  union { float f; unsigned u; } v; v.f = f;
  unsigned r = v.u + 0x7FFFu + ((v.u >> 16) & 1u);
  return (u16)(r >> 16);
}

__device__ __forceinline__ f32x4 mfma_bf16(bf16x8 a, bf16x8 b, f32x4 c){
  return __builtin_amdgcn_mfma_f32_16x16x32_bf16(a, b, c, 0, 0, 0);
}

// ---------------- transpose + fp32->bf16 cast: out[c][r] = in[r][c] ----------------
__global__ void cast_transpose(const float* __restrict__ in, u16* __restrict__ out,
                               int R, int Cc, int rstride, int d1,
                               long long s_hi, long long s_lo)
{
  __shared__ float tile[32][33];
  int z = blockIdx.z;
  in += (long long)(z / d1) * s_hi + (long long)(z % d1) * s_lo;
  out += (size_t)z * R * Cc;
  int tx = threadIdx.x & 31, ty = threadIdx.x >> 5;   // 32 x 8
  int r0 = blockIdx.y * 32, c0 = blockIdx.x * 32;
  #pragma unroll
  for(int i=0;i<4;i++){
    int r = r0 + ty + i*8;
    if(r < R && c0 + tx < Cc) tile[ty + i*8][tx] = in[(size_t)r * rstride + c0 + tx];
  }
  __syncthreads();
  #pragma unroll
  for(int i=0;i<4;i++){
    int c = c0 + ty + i*8;
    if(c < Cc && r0 + tx < R) out[(size_t)c * R + r0 + tx] = f2bf(tile[tx][ty + i*8]);
  }
}

// ---------------- RMSNorm over C=2048, write bf16 (+ optional fp32) ----------------
__global__ void rmsnorm_kernel(const float* __restrict__ x, const float* __restrict__ w,
                               u16* __restrict__ outb, float* __restrict__ outf)
{
  __shared__ float sbuf[4];
  int row = blockIdx.x;
  const float* xr = x + (size_t)row * CDIM;
  int t0 = threadIdx.x * 8;
  float4 v0 = *(const float4*)(xr + t0);
  float4 v1 = *(const float4*)(xr + t0 + 4);
  float a[8] = {v0.x,v0.y,v0.z,v0.w,v1.x,v1.y,v1.z,v1.w};
  float ss = 0.f;
  #pragma unroll
  for(int i=0;i<8;i++) ss += a[i]*a[i];
  #pragma unroll
  for(int o=32;o>0;o>>=1) ss += __shfl_xor(ss, o);
  if((threadIdx.x & 63) == 0) sbuf[threadIdx.x >> 6] = ss;
  __syncthreads();
  float tot = sbuf[0]+sbuf[1]+sbuf[2]+sbuf[3];
  float r = rsqrtf(tot * (1.0f/CDIM) + 1e-6f);
  float4 w0 = *(const float4*)(w + t0);
  float4 w1 = *(const float4*)(w + t0 + 4);
  float wv[8] = {w0.x,w0.y,w0.z,w0.w,w1.x,w1.y,w1.z,w1.w};
  #pragma unroll
  for(int i=0;i<8;i++){
    float o = a[i] * r * wv[i];
    outb[(size_t)row*CDIM + t0 + i] = f2bf(o);
    if(outf) outf[(size_t)row*CDIM + t0 + i] = o;
  }
}

// ---------------- GEMM: C[MxN] = A[MxK]bf16 @ Bt[NxK]bf16 (+addsrc) -> fp32 --------
__global__ __launch_bounds__(256) void gemm_bt(const u16* __restrict__ A,
                                               const u16* __restrict__ Bt,
                                               float* __restrict__ C,
                                               const float* __restrict__ addsrc,
                                               int M, int N, int K)
{
  __shared__ u16 As[64][80];
  __shared__ u16 Bs[64][80];
  int tid = threadIdx.x;
  int br = blockIdx.y*64, bc = blockIdx.x*64;
  int w = tid>>6, lane = tid&63, wr = w>>1, wc = w&1, g = lane>>4, cl = lane&15;
  f32x4 zero = {0.f,0.f,0.f,0.f};
  f32x4 acc[2][2];
  acc[0][0]=acc[0][1]=acc[1][0]=acc[1][1]=zero;
  for(int k0=0;k0<K;k0+=64){
    #pragma unroll
    for(int s=0;s<2;s++){
      int cid = tid + s*256;
      int r = cid>>3, c8 = (cid&7)*8;
      *(uint4*)&As[r][c8] = *(const uint4*)(A + (size_t)(br+r)*K + k0 + c8);
      *(uint4*)&Bs[r][c8] = *(const uint4*)(Bt + (size_t)(bc+r)*K + k0 + c8);
    }
    __syncthreads();
    #pragma unroll
    for(int kk=0;kk<64;kk+=32){
      bf16x8 af[2], bfr[2];
      #pragma unroll
      for(int m=0;m<2;m++) af[m] = *(const bf16x8*)&As[wr*32 + m*16 + cl][kk + g*8];
      #pragma unroll
      for(int n=0;n<2;n++) bfr[n] = *(const bf16x8*)&Bs[wc*32 + n*16 + cl][kk + g*8];
      #pragma unroll
      for(int m=0;m<2;m++)
        #pragma unroll
        for(int n=0;n<2;n++)
          acc[m][n] = mfma_bf16(af[m], bfr[n], acc[m][n]);
    }
    __syncthreads();
  }
  #pragma unroll
  for(int m=0;m<2;m++)
    #pragma unroll
    for(int n=0;n<2;n++)
      #pragma unroll
      for(int j=0;j<4;j++){
        int row = br + wr*32 + m*16 + g*4 + j;
        int col = bc + wc*32 + n*16 + cl;
        float v = acc[m][n][j];
        if(addsrc) v += addsrc[(size_t)row*N + col];
        C[(size_t)row*N + col] = v;
      }
}

// ---------------- per-head RMSNorm (D=128) + RoPE for q,k -> bf16 ------------------
__global__ void qk_norm_rope(const float* __restrict__ qkv, const float* __restrict__ cosb,
                             const float* __restrict__ sinb, const float* __restrict__ qnw,
                             const float* __restrict__ knw,
                             u16* __restrict__ qb, u16* __restrict__ kb)
{
  __shared__ float red[2];
  __shared__ float buf[128];
  int bt = blockIdx.x;             // b*T + t
  int head = blockIdx.y;           // 0..39 : 32 q heads then 8 kv heads
  int d = threadIdx.x;             // 0..127
  int b = bt >> 10, t = bt & 1023;
  bool isq = head < NH;
  const float* src = qkv + (size_t)bt*6144 + (isq ? head*DH : 4096 + (head-NH)*DH);
  float v = src[d];
  float ss = v*v;
  #pragma unroll
  for(int o=32;o>0;o>>=1) ss += __shfl_xor(ss, o);
  if((threadIdx.x & 63) == 0) red[threadIdx.x >> 6] = ss;
  __syncthreads();
  float tot = red[0] + red[1];
  float r = rsqrtf(tot * (1.0f/DH) + 1e-6f);
  float nv = v * r * (isq ? qnw[d] : knw[d]);
  buf[d] = nv;
  __syncthreads();
  float rot = (d < 64) ? -buf[d+64] : buf[d-64];
  float cs = cosb[(size_t)bt*DH + d], sn = sinb[(size_t)bt*DH + d];
  float ov = nv*cs + rot*sn;
  if(isq) qb[(((size_t)b*NH  + head)     *TSEQ + t)*DH + d] = f2bf(ov);
  else    kb[(((size_t)b*NKV + (head-NH))*TSEQ + t)*DH + d] = f2bf(ov);
}

// ---------------- flash attention: grid (T/64, H, B), 4 waves, 16 q-rows/wave ------
__global__ __launch_bounds__(256) void attn_kernel(const u16* __restrict__ qb,
                                                   const u16* __restrict__ kb,
                                                   const u16* __restrict__ vt,
                                                   u16* __restrict__ aob)
{
  __shared__ u16 plds[4][16][32];
  int w = threadIdx.x>>6, lane = threadIdx.x&63;
  int g = lane>>4, cl = lane&15;
  int b = blockIdx.z, h = blockIdx.y;
  int q0 = blockIdx.x*64 + w*16;
  int kvh = h >> 2;                       // H/KV = 4
  const u16* qp = qb + (((size_t)b*NH  + h  )*TSEQ)*DH;
  const u16* kp = kb + (((size_t)b*NKV + kvh)*TSEQ)*DH;
  const u16* vp = vt + (((size_t)b*NKV + kvh)*DH)*TSEQ;
  int qr = q0 + cl;
  bf16x8 aq[4];
  #pragma unroll
  for(int kd=0;kd<4;kd++) aq[kd] = *(const bf16x8*)(qp + (size_t)qr*DH + kd*32 + g*8);
  f32x4 zero = {0.f,0.f,0.f,0.f};
  f32x4 accO[8];
  #pragma unroll
  for(int t=0;t<8;t++) accO[t]=zero;
  float m_r[4], l_r[4];
  #pragma unroll
  for(int j=0;j<4;j++){ m_r[j] = -1e30f; l_r[j] = 0.f; }
  const float scale = 0.08838834764831845f; // 1/sqrt(128)
  int kvend = q0 + 16;
  for(int kv0=0; kv0<kvend; kv0+=32){
    f32x4 s0 = zero, s1 = zero;
    #pragma unroll
    for(int kd=0;kd<4;kd++){
      bf16x8 bk0 = *(const bf16x8*)(kp + (size_t)(kv0 + cl)*DH      + kd*32 + g*8);
      bf16x8 bk1 = *(const bf16x8*)(kp + (size_t)(kv0 + 16 + cl)*DH + kd*32 + g*8);
      s0 = mfma_bf16(aq[kd], bk0, s0);
      s1 = mfma_bf16(aq[kd], bk1, s1);
    }
    float p0[4], p1[4], tmax[4];
    #pragma unroll
    for(int j=0;j<4;j++){
      int rowq = q0 + g*4 + j;
      float a0 = s0[j]*scale; if(kv0 + cl      > rowq) a0 = -1e30f;
      float a1 = s1[j]*scale; if(kv0 + 16 + cl > rowq) a1 = -1e30f;
      p0[j]=a0; p1[j]=a1;
      tmax[j] = fmaxf(a0,a1);
    }
    #pragma unroll
    for(int o=1;o<16;o<<=1)
      #pragma unroll
      for(int j=0;j<4;j++) tmax[j] = fmaxf(tmax[j], __shfl_xor(tmax[j], o));
    float lsum[4];
    #pragma unroll
    for(int j=0;j<4;j++){
      float mn = fmaxf(m_r[j], tmax[j]);
      float f  = __expf(m_r[j]-mn);
      float e0 = __expf(p0[j]-mn), e1 = __expf(p1[j]-mn);
      p0[j]=e0; p1[j]=e1;
      lsum[j] = e0+e1;
      l_r[j] *= f;
      m_r[j] = mn;
      #pragma unroll
      for(int t=0;t<8;t++) accO[t][j] *= f;
    }
    #pragma unroll
    for(int o=1;o<16;o<<=1)
      #pragma unroll
      for(int j=0;j<4;j++) lsum[j] += __shfl_xor(lsum[j], o);
    #pragma unroll
    for(int j=0;j<4;j++) l_r[j] += lsum[j];
    #pragma unroll
    for(int j=0;j<4;j++){
      plds[w][g*4+j][cl]      = f2bf(p0[j]);
      plds[w][g*4+j][16+cl]   = f2bf(p1[j]);
    }
    bf16x8 pa = *(const bf16x8*)&plds[w][cl][g*8];
    #pragma unroll
    for(int t=0;t<8;t++){
      bf16x8 bv = *(const bf16x8*)(vp + (size_t)(t*16+cl)*TSEQ + kv0 + g*8);
      accO[t] = mfma_bf16(pa, bv, accO[t]);
    }
  }
  #pragma unroll
  for(int t=0;t<8;t++)
    #pragma unroll
    for(int j=0;j<4;j++){
      int rowq = q0 + g*4 + j;
      float v = accO[t][j] / l_r[j];
      aob[((size_t)b*TSEQ + rowq)*(NH*DH) + h*DH + t*16 + cl] = f2bf(v);
    }
}

// ---------------- routing: gate logits, softmax, top-2, bucket ---------------------
__global__ void route_kernel(const float* __restrict__ h2f, const float* __restrict__ gw,
                             int* __restrict__ cnt, int* __restrict__ bidx,
                             float* __restrict__ bw)
{
  int lane = threadIdx.x & 63;
  int token = blockIdx.x*4 + (threadIdx.x >> 6);
  float acc[8];
  #pragma unroll
  for(int e=0;e<8;e++) acc[e]=0.f;
  for(int c0 = lane*4; c0 < CDIM; c0 += 256){
    float4 hv = *(const float4*)(h2f + (size_t)token*CDIM + c0);
    float hvv[4] = {hv.x,hv.y,hv.z,hv.w};
    #pragma unroll
    for(int i=0;i<4;i++){
      const float* gr = gw + (size_t)(c0+i)*NE;
      #pragma unroll
      for(int e=0;e<8;e++) acc[e] += hvv[i]*gr[e];
    }
  }
  #pragma unroll
  for(int o=32;o>0;o>>=1)
    #pragma unroll
    for(int e=0;e<8;e++) acc[e] += __shfl_xor(acc[e], o);
  if(lane==0){
    float mx = acc[0];
    #pragma unroll
    for(int e=1;e<8;e++) mx = fmaxf(mx, acc[e]);
    float rw[8]; float s=0.f;
    #pragma unroll
    for(int e=0;e<8;e++){ rw[e] = __expf(acc[e]-mx); s += rw[e]; }
    #pragma unroll
    for(int e=0;e<8;e++) rw[e] /= s;
    int i0=0;
    #pragma unroll
    for(int e=1;e<8;e++) if(rw[e] > rw[i0]) i0=e;
    int i1 = (i0==0)?1:0;
    #pragma unroll
    for(int e=0;e<8;e++) if(e!=i0 && rw[e] > rw[i1]) i1=e;
    float tw0=rw[i0], tw1=rw[i1];
    float s1 = tw0+tw1+1e-9f;
    float a0 = tw0/s1, a1 = tw1/s1;
    float s2 = a0+a1+1e-9f;
    float w0 = a0/s2, w1 = a1/s2;
    int sl0 = atomicAdd(&cnt[i0],1);
    bidx[i0*CAP + sl0] = token; bw[i0*CAP + sl0] = w0;
    int sl1 = atomicAdd(&cnt[i1],1);
    bidx[i1*CAP + sl1] = token; bw[i1*CAP + sl1] = w1;
  }
}

// ---------------- MoE gate_up GEMM (gathered rows) + SiLU, out act bf16 ------------
__global__ __launch_bounds__(256) void gemm_gateup(const u16* __restrict__ h2b,
                                                   const u16* __restrict__ gupT,
                                                   u16* __restrict__ act,
                                                   const int* __restrict__ bidx,
                                                   const int* __restrict__ cnt)
{
  int e = blockIdx.z;
  int nc = cnt[e];
  int sr = blockIdx.y*64;
  if(sr >= nc) return;
  const int K = CDIM;
  const u16* Btg = gupT + (size_t)e*1536*CDIM;
  const u16* Btu = Btg + (size_t)768*CDIM;
  const int* be = bidx + e*CAP;
  __shared__ u16 As[64][80];
  __shared__ u16 Bg[64][80];
  __shared__ u16 Bu[64][80];
  int tid = threadIdx.x;
  int bc = blockIdx.x*64;
  int w = tid>>6, lane = tid&63, wr = w>>1, wc = w&1, g = lane>>4, cl = lane&15;
  int r0_ = tid>>3, c8 = (tid&7)*8;
  int tok0 = be[sr + r0_];      if(tok0 < 0 || tok0 >= NTOK) tok0 = 0;
  int tok1 = be[sr + r0_ + 32]; if(tok1 < 0 || tok1 >= NTOK) tok1 = 0;
  f32x4 zero = {0.f,0.f,0.f,0.f};
  f32x4 accG[2][2], accU[2][2];
  accG[0][0]=accG[0][1]=accG[1][0]=accG[1][1]=zero;
  accU[0][0]=accU[0][1]=accU[1][0]=accU[1][1]=zero;
  for(int k0=0;k0<K;k0+=64){
    *(uint4*)&As[r0_][c8]    = *(const uint4*)(h2b + (size_t)tok0*K + k0 + c8);
    *(uint4*)&As[r0_+32][c8] = *(const uint4*)(h2b + (size_t)tok1*K + k0 + c8);
    *(uint4*)&Bg[r0_][c8]    = *(const uint4*)(Btg + (size_t)(bc+r0_)*K + k0 + c8);
    *(uint4*)&Bg[r0_+32][c8] = *(const uint4*)(Btg + (size_t)(bc+r0_+32)*K + k0 + c8);
    *(uint4*)&Bu[r0_][c8]    = *(const uint4*)(Btu + (size_t)(bc+r0_)*K + k0 + c8);
    *(uint4*)&Bu[r0_+32][c8] = *(const uint4*)(Btu + (size_t)(bc+r0_+32)*K + k0 + c8);
    __syncthreads();
    #pragma unroll
    for(int kk=0;kk<64;kk+=32){
      bf16x8 af[2], bg[2], bu[2];
      #pragma unroll
      for(int m=0;m<2;m++) af[m] = *(const bf16x8*)&As[wr*32 + m*16 + cl][kk + g*8];
      #pragma unroll
      for(int n=0;n<2;n++){
        bg[n] = *(const bf16x8*)&Bg[wc*32 + n*16 + cl][kk + g*8];
        bu[n] = *(const bf16x8*)&Bu[wc*32 + n*16 + cl][kk + g*8];
      }
      #pragma unroll
      for(int m=0;m<2;m++)
        #pragma unroll
        for(int n=0;n<2;n++){
          accG[m][n] = mfma_bf16(af[m], bg[n], accG[m][n]);
          accU[m][n] = mfma_bf16(af[m], bu[n], accU[m][n]);
        }
    }
    __syncthreads();
  }
  #pragma unroll
  for(int m=0;m<2;m++)
    #pragma unroll
    for(int n=0;n<2;n++)
      #pragma unroll
      for(int j=0;j<4;j++){
        int slot = sr + wr*32 + m*16 + g*4 + j;
        int col  = bc + wc*32 + n*16 + cl;
        float gv = accG[m][n][j], uv = accU[m][n][j];
        float av = gv / (1.f + __expf(-gv)) * uv;
        act[((size_t)e*CAP + slot)*FDIM + col] = f2bf(av);
      }
}

// ---------------- MoE down GEMM, scatter-accumulate with routing weight ------------
__global__ __launch_bounds__(256) void gemm_down(const u16* __restrict__ act,
                                                 const u16* __restrict__ downT,
                                                 float* __restrict__ out,
                                                 const int* __restrict__ bidx,
                                                 const float* __restrict__ bw,
                                                 const int* __restrict__ cnt)
{
  int e = blockIdx.z;
  int nc = cnt[e];
  int sr = blockIdx.y*64;
  if(sr >= nc) return;
  const int K = FDIM;
  const u16* A  = act   + (size_t)e*CAP*FDIM;
  const u16* Bt = downT + (size_t)e*CDIM*FDIM;
  const int* be = bidx + e*CAP;
  const float* bwe = bw + e*CAP;
  __shared__ u16 As[64][80];
  __shared__ u16 Bs[64][80];
  int tid = threadIdx.x;
  int bc = blockIdx.x*64;
  int w = tid>>6, lane = tid&63, wr = w>>1, wc = w&1, g = lane>>4, cl = lane&15;
  f32x4 zero = {0.f,0.f,0.f,0.f};
  f32x4 acc[2][2];
  acc[0][0]=acc[0][1]=acc[1][0]=acc[1][1]=zero;
  for(int k0=0;k0<K;k0+=64){
    #pragma unroll
    for(int s=0;s<2;s++){
      int cid = tid + s*256;
      int r = cid>>3, c8 = (cid&7)*8;
      *(uint4*)&As[r][c8] = *(const uint4*)(A  + (size_t)(sr+r)*K + k0 + c8);
      *(uint4*)&Bs[r][c8] = *(const uint4*)(Bt + (size_t)(bc+r)*K + k0 + c8);
    }
    __syncthreads();
    #pragma unroll
    for(int kk=0;kk<64;kk+=32){
      bf16x8 af[2], bfr[2];
      #pragma unroll
      for(int m=0;m<2;m++) af[m] = *(const bf16x8*)&As[wr*32 + m*16 + cl][kk + g*8];
      #pragma unroll
      for(int n=0;n<2;n++) bfr[n] = *(const bf16x8*)&Bs[wc*32 + n*16 + cl][kk + g*8];
      #pragma unroll
      for(int m=0;m<2;m++)
        #pragma unroll
        for(int n=0;n<2;n++)
          acc[m][n] = mfma_bf16(af[m], bfr[n], acc[m][n]);
    }
    __syncthreads();
  }
  #pragma unroll
  for(int m=0;m<2;m++)
    #pragma unroll
    for(int n=0;n<2;n++)
      #pragma unroll
      for(int j=0;j<4;j++){
        int slot = sr + wr*32 + m*16 + g*4 + j;
        if(slot < nc){
          int tok = be[slot];
          float wgt = bwe[slot];
          int col = bc + wc*32 + n*16 + cl;
          atomicAdd(out + (size_t)tok*CDIM + col, wgt * acc[m][n][j]);
        }
      }
}

// ------------------------------------ launch ---------------------------------------
extern "C" void kernel_launch(void* const* d_in, const int* in_sizes, int n_in,
                              void* d_out, int out_size, void* d_ws, size_t ws_size,
                              hipStream_t stream)
{
  const float* x     = (const float*)d_in[0];
  const float* cosb  = (const float*)d_in[1];
  const float* sinb  = (const float*)d_in[2];
  const float* ln1w  = (const float*)d_in[3];
  const float* qw    = (const float*)d_in[4];
  const float* kw    = (const float*)d_in[5];
  const float* vw    = (const float*)d_in[6];
  const float* ow    = (const float*)d_in[7];
  const float* qnw   = (const float*)d_in[8];
  const float* knw   = (const float*)d_in[9];
  const float* ln2w  = (const float*)d_in[10];
  const float* gatew = (const float*)d_in[11];
  const float* gupw  = (const float*)d_in[12];
  const float* downw = (const float*)d_in[13];
  float* out = (float*)d_out;

  char* ws = (char*)d_ws;
  size_t off = 0;
  auto alloc = [&](size_t bytes)->char*{
    char* p = ws + off;
    off = (off + bytes + 255) & ~(size_t)255;
    return p;
  };
  u16*   wqkvT = (u16*)  alloc((size_t)6144*2048*2);
  u16*   owT   = (u16*)  alloc((size_t)2048*4096*2);
  u16*   gupT  = (u16*)  alloc((size_t)8*1536*2048*2);
  u16*   downT = (u16*)  alloc((size_t)8*2048*768*2);
  u16*   h1b   = (u16*)  alloc((size_t)2048*2048*2);
  float* qkvf  = (float*)alloc((size_t)2048*6144*4);
  u16*   qb    = (u16*)  alloc((size_t)2*32*1024*128*2);
  u16*   kb    = (u16*)  alloc((size_t)2*8*1024*128*2);
  u16*   vt    = (u16*)  alloc((size_t)2*8*1024*128*2);
  u16*   aob   = (u16*)  alloc((size_t)2048*4096*2);
  float* h2f   = (float*)alloc((size_t)2048*2048*4);
  u16*   h2b   = (u16*)  alloc((size_t)2048*2048*2);
  u16*   actb  = (u16*)  alloc((size_t)8*2048*768*2);
  int*   bidx  = (int*)  alloc((size_t)8*2048*4);
  float* bwgt  = (float*)alloc((size_t)8*2048*4);
  int*   cnt   = (int*)  alloc(64);
  (void)ws_size; (void)in_sizes; (void)n_in; (void)out_size;

  hipMemsetAsync(cnt, 0, 8*sizeof(int), stream);

  // weight transposes/casts
  cast_transpose<<<dim3(128,64,1), 256, 0, stream>>>(qw, wqkvT,                  2048, 4096, 4096, 1, 0, 0);
  cast_transpose<<<dim3(32, 64,1), 256, 0, stream>>>(kw, wqkvT + (size_t)4096*2048, 2048, 1024, 1024, 1, 0, 0);
  cast_transpose<<<dim3(32, 64,1), 256, 0, stream>>>(vw, wqkvT + (size_t)5120*2048, 2048, 1024, 1024, 1, 0, 0);
  cast_transpose<<<dim3(64,128,1), 256, 0, stream>>>(ow, owT,                    4096, 2048, 2048, 1, 0, 0);
  cast_transpose<<<dim3(48, 64,8), 256, 0, stream>>>(gupw, gupT,                 2048, 1536, 1536, 8, 0, (long long)2048*1536);
  cast_transpose<<<dim3(64, 24,8), 256, 0, stream>>>(downw, downT,               768,  2048, 2048, 8, 0, (long long)768*2048);

  // ln1 + cast
  rmsnorm_kernel<<<2048, 256, 0, stream>>>(x, ln1w, h1b, nullptr);
  // qkv = h @ [q|k|v]
  gemm_bt<<<dim3(96,32), 256, 0, stream>>>(h1b, wqkvT, qkvf, nullptr, 2048, 6144, 2048);
  // q/k: per-head rmsnorm + rope -> bf16
  qk_norm_rope<<<dim3(2048,40), 128, 0, stream>>>(qkvf, cosb, sinb, qnw, knw, qb, kb);
  // v -> (b,kv,D,T) bf16
  cast_transpose<<<dim3(4,32,16), 256, 0, stream>>>(qkvf + 5120, vt, 1024, 128, 6144, 8,
                                                    (long long)1024*6144, 128);
  // attention
  attn_kernel<<<dim3(16,32,2), 256, 0, stream>>>(qb, kb, vt, aob);
  // o-proj + residual -> d_out (= x1)
  gemm_bt<<<dim3(32,32), 256, 0, stream>>>(aob, owT, out, x, 2048, 2048, 4096);
  // ln2 (fp32 + bf16)
  rmsnorm_kernel<<<2048, 256, 0, stream>>>(out, ln2w, h2b, h2f);
  // routing
  route_kernel<<<512, 256, 0, stream>>>(h2f, gatew, cnt, bidx, bwgt);
  // experts
  gemm_gateup<<<dim3(12,32,8), 256, 0, stream>>>(h2b, gupT, actb, bidx, cnt);
  gemm_down<<<dim3(32,32,8), 256, 0, stream>>>(actb, downT, out, bidx, bwgt, cnt);
}

// Round 3
// 711.973 us; speedup vs baseline: 1.2277x; 1.2277x over previous
//
#include <hip/hip_runtime.h>
#include <hip/hip_bf16.h>

typedef short bf16x8 __attribute__((ext_vector_type(8)));
typedef float f32x4 __attribute__((ext_vector_type(4)));
typedef unsigned short u16;

#define NTOK 2048
#define CDIM 2048
#define TSEQ 1024
#define NH   32
#define NKV  8
#define DH   128
#define NE   8
#define FDIM 768
#define CAP  2048

#define GLOAD_LDS16(g, l) \
  __builtin_amdgcn_global_load_lds((const __attribute__((address_space(1))) void*)(g), \
                                   (__attribute__((address_space(3))) void*)(l), 16, 0, 0)

__device__ __forceinline__ u16 f2bf(float f){
  union { float f; unsigned u; } v; v.f = f;
  unsigned r = v.u + 0x7FFFu + ((v.u >> 16) & 1u);
  return (u16)(r >> 16);
}

__device__ __forceinline__ f32x4 mfma_bf16(bf16x8 a, bf16x8 b, f32x4 c){
  return __builtin_amdgcn_mfma_f32_16x16x32_bf16(a, b, c, 0, 0, 0);
}

// ---------------- transpose + fp32->bf16 cast: out[c][r] = in[r][c] ----------------
__global__ void cast_transpose(const float* __restrict__ in, u16* __restrict__ out,
                               int R, int Cc, int rstride, int d1,
                               long long s_hi, long long s_lo)
{
  __shared__ float tile[32][33];
  int z = blockIdx.z;
  in += (long long)(z / d1) * s_hi + (long long)(z % d1) * s_lo;
  out += (size_t)z * R * Cc;
  int tx = threadIdx.x & 31, ty = threadIdx.x >> 5;   // 32 x 8
  int r0 = blockIdx.y * 32, c0 = blockIdx.x * 32;
  #pragma unroll
  for(int i=0;i<4;i++){
    int r = r0 + ty + i*8;
    if(r < R && c0 + tx < Cc) tile[ty + i*8][tx] = in[(size_t)r * rstride + c0 + tx];
  }
  __syncthreads();
  #pragma unroll
  for(int i=0;i<4;i++){
    int c = c0 + ty + i*8;
    if(c < Cc && r0 + tx < R) out[(size_t)c * R + r0 + tx] = f2bf(tile[tx][ty + i*8]);
  }
}

// ---------------- RMSNorm over C=2048, write bf16 (+ optional fp32) ----------------
__global__ void rmsnorm_kernel(const float* __restrict__ x, const float* __restrict__ w,
                               u16* __restrict__ outb, float* __restrict__ outf)
{
  __shared__ float sbuf[4];
  int row = blockIdx.x;
  const float* xr = x + (size_t)row * CDIM;
  int t0 = threadIdx.x * 8;
  float4 v0 = *(const float4*)(xr + t0);
  float4 v1 = *(const float4*)(xr + t0 + 4);
  float a[8] = {v0.x,v0.y,v0.z,v0.w,v1.x,v1.y,v1.z,v1.w};
  float ss = 0.f;
  #pragma unroll
  for(int i=0;i<8;i++) ss += a[i]*a[i];
  #pragma unroll
  for(int o=32;o>0;o>>=1) ss += __shfl_xor(ss, o);
  if((threadIdx.x & 63) == 0) sbuf[threadIdx.x >> 6] = ss;
  __syncthreads();
  float tot = sbuf[0]+sbuf[1]+sbuf[2]+sbuf[3];
  float r = rsqrtf(tot * (1.0f/CDIM) + 1e-6f);
  float4 w0 = *(const float4*)(w + t0);
  float4 w1 = *(const float4*)(w + t0 + 4);
  float wv[8] = {w0.x,w0.y,w0.z,w0.w,w1.x,w1.y,w1.z,w1.w};
  #pragma unroll
  for(int i=0;i<8;i++){
    float o = a[i] * r * wv[i];
    outb[(size_t)row*CDIM + t0 + i] = f2bf(o);
    if(outf) outf[(size_t)row*CDIM + t0 + i] = o;
  }
}

// ---------------- GEMM 128x128 (m97 structure): C = A[MxK] @ Bt[NxK]^T -------------
__global__ __launch_bounds__(256) void gemm128(const u16* __restrict__ A,
                                               const u16* __restrict__ Bt,
                                               float* __restrict__ C,
                                               const float* __restrict__ addsrc,
                                               int M, int N, int K)
{
  __shared__ u16 As[128][64];
  __shared__ u16 Bs[128][64];
  int tid = threadIdx.x;
  int w = tid>>6, lane = tid&63, g = lane>>4, cl = lane&15;
  int wr = w>>1, wc = w&1;
  int br = blockIdx.y*128, bc = blockIdx.x*128;
  int lrow = lane>>3, lcol = (lane&7)*8;
  f32x4 acc[4][4];
  #pragma unroll
  for(int m=0;m<4;m++)
    #pragma unroll
    for(int n=0;n<4;n++) acc[m][n] = (f32x4){0.f,0.f,0.f,0.f};
  for(int k0=0;k0<K;k0+=64){
    #pragma unroll
    for(int i=0;i<4;i++){
      int seg = w*4 + i;
      int r = seg*8 + lrow;
      GLOAD_LDS16(A  + (size_t)(br+r)*K + k0 + lcol, &As[seg*8][0]);
      GLOAD_LDS16(Bt + (size_t)(bc+r)*K + k0 + lcol, &Bs[seg*8][0]);
    }
    __syncthreads();
    #pragma unroll
    for(int kk=0;kk<64;kk+=32){
      bf16x8 af[4], bfr[4];
      #pragma unroll
      for(int m=0;m<4;m++) af[m]  = *(const bf16x8*)&As[wr*64 + m*16 + cl][kk + g*8];
      #pragma unroll
      for(int n=0;n<4;n++) bfr[n] = *(const bf16x8*)&Bs[wc*64 + n*16 + cl][kk + g*8];
      #pragma unroll
      for(int m=0;m<4;m++)
        #pragma unroll
        for(int n=0;n<4;n++)
          acc[m][n] = mfma_bf16(af[m], bfr[n], acc[m][n]);
    }
    __syncthreads();
  }
  #pragma unroll
  for(int m=0;m<4;m++)
    #pragma unroll
    for(int n=0;n<4;n++)
      #pragma unroll
      for(int j=0;j<4;j++){
        int row = br + wr*64 + m*16 + g*4 + j;
        int col = bc + wc*64 + n*16 + cl;
        float v = acc[m][n][j];
        if(addsrc) v += addsrc[(size_t)row*N + col];
        C[(size_t)row*N + col] = v;
      }
}

// ---------------- per-head RMSNorm (D=128) + RoPE for q,k -> bf16 ------------------
__global__ void qk_norm_rope(const float* __restrict__ qkv, const float* __restrict__ cosb,
                             const float* __restrict__ sinb, const float* __restrict__ qnw,
                             const float* __restrict__ knw,
                             u16* __restrict__ qb, u16* __restrict__ kb)
{
  __shared__ float red[2];
  __shared__ float buf[128];
  int bt = blockIdx.x;             // b*T + t
  int head = blockIdx.y;           // 0..39 : 32 q heads then 8 kv heads
  int d = threadIdx.x;             // 0..127
  int b = bt >> 10, t = bt & 1023;
  bool isq = head < NH;
  const float* src = qkv + (size_t)bt*6144 + (isq ? head*DH : 4096 + (head-NH)*DH);
  float v = src[d];
  float ss = v*v;
  #pragma unroll
  for(int o=32;o>0;o>>=1) ss += __shfl_xor(ss, o);
  if((threadIdx.x & 63) == 0) red[threadIdx.x >> 6] = ss;
  __syncthreads();
  float tot = red[0] + red[1];
  float r = rsqrtf(tot * (1.0f/DH) + 1e-6f);
  float nv = v * r * (isq ? qnw[d] : knw[d]);
  buf[d] = nv;
  __syncthreads();
  float rot = (d < 64) ? -buf[d+64] : buf[d-64];
  float cs = cosb[(size_t)bt*DH + d], sn = sinb[(size_t)bt*DH + d];
  float ov = nv*cs + rot*sn;
  if(isq) qb[(((size_t)b*NH  + head)     *TSEQ + t)*DH + d] = f2bf(ov);
  else    kb[(((size_t)b*NKV + (head-NH))*TSEQ + t)*DH + d] = f2bf(ov);
}

// ---- flash attention: block = 4 q-heads (one KV group) x 32 q-rows, KV step 64 ----
// grid (T/32, KV, B), 256 threads. K/V staged in LDS shared by the 4 waves.
__global__ __launch_bounds__(256) void attn_kernel(const u16* __restrict__ qb,
                                                   const u16* __restrict__ kb,
                                                   const u16* __restrict__ vt,
                                                   u16* __restrict__ aob)
{
  __shared__ u16 Ks[64][136];       // K tile  [kv][d], pad 8
  __shared__ u16 Vs[128][72];       // V^T tile [d][kv], pad 8
  __shared__ u16 Ps[4][32][72];     // per-wave P tile [qrow][kv], pad 8
  int tid = threadIdx.x;
  int w = tid>>6, lane = tid&63, g = lane>>4, cl = lane&15;
  int b = blockIdx.z, kvh = blockIdx.y;
  int qt = (gridDim.x - 1) - blockIdx.x;     // big tiles first
  int q0 = qt*32;
  int h = kvh*4 + w;
  const u16* qp = qb + (((size_t)b*NH  + h  )*TSEQ)*DH;
  const u16* kp = kb + (((size_t)b*NKV + kvh)*TSEQ)*DH;
  const u16* vp = vt + (((size_t)b*NKV + kvh)*DH)*TSEQ;
  // Q fragments: rows q0 + m*16 + cl
  bf16x8 aq[2][4];
  #pragma unroll
  for(int m=0;m<2;m++)
    #pragma unroll
    for(int kd=0;kd<4;kd++)
      aq[m][kd] = *(const bf16x8*)(qp + (size_t)(q0 + m*16 + cl)*DH + kd*32 + g*8);
  f32x4 accO[2][8];
  #pragma unroll
  for(int m=0;m<2;m++)
    #pragma unroll
    for(int n=0;n<8;n++) accO[m][n] = (f32x4){0.f,0.f,0.f,0.f};
  float mr[2][4], lr[2][4];
  #pragma unroll
  for(int m=0;m<2;m++)
    #pragma unroll
    for(int j=0;j<4;j++){ mr[m][j] = -1e30f; lr[m][j] = 0.f; }
  const float scale = 0.08838834764831845f; // 1/sqrt(128)
  for(int kv0 = 0; kv0 < q0 + 32; kv0 += 64){
    // ---- cooperative stage: K 64x128 (1024 x 16B chunks), V^T 128x64 (1024 chunks) ----
    #pragma unroll
    for(int it=0; it<4; it++){
      int c = tid + it*256;
      int kr = c>>4, kcol = (c&15)*8;
      *(uint4*)&Ks[kr][kcol] = *(const uint4*)(kp + (size_t)(kv0 + kr)*DH + kcol);
      int vr = c>>3, vcol = (c&7)*8;
      *(uint4*)&Vs[vr][vcol] = *(const uint4*)(vp + (size_t)vr*TSEQ + kv0 + vcol);
    }
    __syncthreads();
    // ---- QK^T : 32 MFMAs ----
    f32x4 sc[2][4];
    #pragma unroll
    for(int m=0;m<2;m++)
      #pragma unroll
      for(int n=0;n<4;n++) sc[m][n] = (f32x4){0.f,0.f,0.f,0.f};
    #pragma unroll
    for(int kd=0;kd<4;kd++){
      bf16x8 bk[4];
      #pragma unroll
      for(int n=0;n<4;n++) bk[n] = *(const bf16x8*)&Ks[n*16 + cl][kd*32 + g*8];
      #pragma unroll
      for(int m=0;m<2;m++)
        #pragma unroll
        for(int n=0;n<4;n++)
          sc[m][n] = mfma_bf16(aq[m][kd], bk[n], sc[m][n]);
    }
    // ---- scale + causal mask ----
    #pragma unroll
    for(int m=0;m<2;m++)
      #pragma unroll
      for(int n=0;n<4;n++)
        #pragma unroll
        for(int j=0;j<4;j++){
          int row = q0 + m*16 + g*4 + j;
          int col = kv0 + n*16 + cl;
          float v = sc[m][n][j]*scale;
          sc[m][n][j] = (col > row) ? -1e30f : v;
        }
    // ---- row max ----
    float tmax[2][4];
    #pragma unroll
    for(int m=0;m<2;m++)
      #pragma unroll
      for(int j=0;j<4;j++)
        tmax[m][j] = fmaxf(fmaxf(sc[m][0][j], sc[m][1][j]), fmaxf(sc[m][2][j], sc[m][3][j]));
    #pragma unroll
    for(int o=1;o<16;o<<=1)
      #pragma unroll
      for(int m=0;m<2;m++)
        #pragma unroll
        for(int j=0;j<4;j++) tmax[m][j] = fmaxf(tmax[m][j], __shfl_xor(tmax[m][j], o));
    // ---- online update + exp ----
    float fsc[2][4], rsum[2][4];
    #pragma unroll
    for(int m=0;m<2;m++)
      #pragma unroll
      for(int j=0;j<4;j++){
        float mn = fmaxf(mr[m][j], tmax[m][j]);
        float f  = __expf(mr[m][j]-mn);
        mr[m][j] = mn; fsc[m][j] = f;
        float s = 0.f;
        #pragma unroll
        for(int n=0;n<4;n++){
          float e = __expf(sc[m][n][j]-mn);
          sc[m][n][j] = e; s += e;
        }
        rsum[m][j] = s;
      }
    #pragma unroll
    for(int o=1;o<16;o<<=1)
      #pragma unroll
      for(int m=0;m<2;m++)
        #pragma unroll
        for(int j=0;j<4;j++) rsum[m][j] += __shfl_xor(rsum[m][j], o);
    #pragma unroll
    for(int m=0;m<2;m++)
      #pragma unroll
      for(int j=0;j<4;j++) lr[m][j] = lr[m][j]*fsc[m][j] + rsum[m][j];
    #pragma unroll
    for(int m=0;m<2;m++)
      #pragma unroll
      for(int n=0;n<8;n++)
        #pragma unroll
        for(int j=0;j<4;j++) accO[m][n][j] *= fsc[m][j];
    // ---- write P (bf16) to per-wave LDS ----
    #pragma unroll
    for(int m=0;m<2;m++)
      #pragma unroll
      for(int n=0;n<4;n++)
        #pragma unroll
        for(int j=0;j<4;j++)
          Ps[w][m*16 + g*4 + j][n*16 + cl] = f2bf(sc[m][n][j]);
    // ---- PV : 32 MFMAs ----
    bf16x8 pa[2][2];
    #pragma unroll
    for(int m=0;m<2;m++)
      #pragma unroll
      for(int s2=0;s2<2;s2++)
        pa[m][s2] = *(const bf16x8*)&Ps[w][m*16 + cl][s2*32 + g*8];
    #pragma unroll
    for(int n=0;n<8;n++){
      #pragma unroll
      for(int s2=0;s2<2;s2++){
        bf16x8 bv = *(const bf16x8*)&Vs[n*16 + cl][s2*32 + g*8];
        #pragma unroll
        for(int m=0;m<2;m++)
          accO[m][n] = mfma_bf16(pa[m][s2], bv, accO[m][n]);
      }
    }
    __syncthreads();
  }
  // ---- epilogue ----
  #pragma unroll
  for(int m=0;m<2;m++)
    #pragma unroll
    for(int n=0;n<8;n++)
      #pragma unroll
      for(int j=0;j<4;j++){
        int row = q0 + m*16 + g*4 + j;
        float v = accO[m][n][j] / lr[m][j];
        aob[((size_t)b*TSEQ + row)*(NH*DH) + h*DH + n*16 + cl] = f2bf(v);
      }
}

// ---------------- routing: gate logits, softmax, top-2, bucket ---------------------
__global__ void route_kernel(const float* __restrict__ h2f, const float* __restrict__ gw,
                             int* __restrict__ cnt, int* __restrict__ bidx,
                             float* __restrict__ bw)
{
  int lane = threadIdx.x & 63;
  int token = blockIdx.x*4 + (threadIdx.x >> 6);
  float acc[8];
  #pragma unroll
  for(int e=0;e<8;e++) acc[e]=0.f;
  for(int c0 = lane*4; c0 < CDIM; c0 += 256){
    float4 hv = *(const float4*)(h2f + (size_t)token*CDIM + c0);
    float hvv[4] = {hv.x,hv.y,hv.z,hv.w};
    #pragma unroll
    for(int i=0;i<4;i++){
      const float* gr = gw + (size_t)(c0+i)*NE;
      #pragma unroll
      for(int e=0;e<8;e++) acc[e] += hvv[i]*gr[e];
    }
  }
  #pragma unroll
  for(int o=32;o>0;o>>=1)
    #pragma unroll
    for(int e=0;e<8;e++) acc[e] += __shfl_xor(acc[e], o);
  if(lane==0){
    float mx = acc[0];
    #pragma unroll
    for(int e=1;e<8;e++) mx = fmaxf(mx, acc[e]);
    float rw[8]; float s=0.f;
    #pragma unroll
    for(int e=0;e<8;e++){ rw[e] = __expf(acc[e]-mx); s += rw[e]; }
    #pragma unroll
    for(int e=0;e<8;e++) rw[e] /= s;
    int i0=0;
    #pragma unroll
    for(int e=1;e<8;e++) if(rw[e] > rw[i0]) i0=e;
    int i1 = (i0==0)?1:0;
    #pragma unroll
    for(int e=0;e<8;e++) if(e!=i0 && rw[e] > rw[i1]) i1=e;
    float tw0=rw[i0], tw1=rw[i1];
    float s1 = tw0+tw1+1e-9f;
    float a0 = tw0/s1, a1 = tw1/s1;
    float s2 = a0+a1+1e-9f;
    float w0 = a0/s2, w1 = a1/s2;
    int sl0 = atomicAdd(&cnt[i0],1);
    bidx[i0*CAP + sl0] = token; bw[i0*CAP + sl0] = w0;
    int sl1 = atomicAdd(&cnt[i1],1);
    bidx[i1*CAP + sl1] = token; bw[i1*CAP + sl1] = w1;
  }
}

// ---------------- MoE gate_up GEMM (gathered rows) + SiLU, out act bf16 ------------
__global__ __launch_bounds__(256) void gemm_gateup(const u16* __restrict__ h2b,
                                                   const u16* __restrict__ gupT,
                                                   u16* __restrict__ act,
                                                   const int* __restrict__ bidx,
                                                   const int* __restrict__ cnt)
{
  int e = blockIdx.z;
  int nc = cnt[e];
  int sr = blockIdx.y*64;
  if(sr >= nc) return;
  const int K = CDIM;
  const u16* Btg = gupT + (size_t)e*1536*CDIM;
  const u16* Btu = Btg + (size_t)768*CDIM;
  const int* be = bidx + e*CAP;
  __shared__ u16 As[64][80];
  __shared__ u16 Bg[64][80];
  __shared__ u16 Bu[64][80];
  int tid = threadIdx.x;
  int bc = blockIdx.x*64;
  int w = tid>>6, lane = tid&63, wr = w>>1, wc = w&1, g = lane>>4, cl = lane&15;
  int r0_ = tid>>3, c8 = (tid&7)*8;
  int tok0 = be[sr + r0_];      if(tok0 < 0 || tok0 >= NTOK) tok0 = 0;
  int tok1 = be[sr + r0_ + 32]; if(tok1 < 0 || tok1 >= NTOK) tok1 = 0;
  f32x4 zero = {0.f,0.f,0.f,0.f};
  f32x4 accG[2][2], accU[2][2];
  accG[0][0]=accG[0][1]=accG[1][0]=accG[1][1]=zero;
  accU[0][0]=accU[0][1]=accU[1][0]=accU[1][1]=zero;
  for(int k0=0;k0<K;k0+=64){
    *(uint4*)&As[r0_][c8]    = *(const uint4*)(h2b + (size_t)tok0*K + k0 + c8);
    *(uint4*)&As[r0_+32][c8] = *(const uint4*)(h2b + (size_t)tok1*K + k0 + c8);
    *(uint4*)&Bg[r0_][c8]    = *(const uint4*)(Btg + (size_t)(bc+r0_)*K + k0 + c8);
    *(uint4*)&Bg[r0_+32][c8] = *(const uint4*)(Btg + (size_t)(bc+r0_+32)*K + k0 + c8);
    *(uint4*)&Bu[r0_][c8]    = *(const uint4*)(Btu + (size_t)(bc+r0_)*K + k0 + c8);
    *(uint4*)&Bu[r0_+32][c8] = *(const uint4*)(Btu + (size_t)(bc+r0_+32)*K + k0 + c8);
    __syncthreads();
    #pragma unroll
    for(int kk=0;kk<64;kk+=32){
      bf16x8 af[2], bg[2], bu[2];
      #pragma unroll
      for(int m=0;m<2;m++) af[m] = *(const bf16x8*)&As[wr*32 + m*16 + cl][kk + g*8];
      #pragma unroll
      for(int n=0;n<2;n++){
        bg[n] = *(const bf16x8*)&Bg[wc*32 + n*16 + cl][kk + g*8];
        bu[n] = *(const bf16x8*)&Bu[wc*32 + n*16 + cl][kk + g*8];
      }
      #pragma unroll
      for(int m=0;m<2;m++)
        #pragma unroll
        for(int n=0;n<2;n++){
          accG[m][n] = mfma_bf16(af[m], bg[n], accG[m][n]);
          accU[m][n] = mfma_bf16(af[m], bu[n], accU[m][n]);
        }
    }
    __syncthreads();
  }
  #pragma unroll
  for(int m=0;m<2;m++)
    #pragma unroll
    for(int n=0;n<2;n++)
      #pragma unroll
      for(int j=0;j<4;j++){
        int slot = sr + wr*32 + m*16 + g*4 + j;
        int col  = bc + wc*32 + n*16 + cl;
        float gv = accG[m][n][j], uv = accU[m][n][j];
        float av = gv / (1.f + __expf(-gv)) * uv;
        act[((size_t)e*CAP + slot)*FDIM + col] = f2bf(av);
      }
}

// ---------------- MoE down GEMM, scatter-accumulate with routing weight ------------
__global__ __launch_bounds__(256) void gemm_down(const u16* __restrict__ act,
                                                 const u16* __restrict__ downT,
                                                 float* __restrict__ out,
                                                 const int* __restrict__ bidx,
                                                 const float* __restrict__ bw,
                                                 const int* __restrict__ cnt)
{
  int e = blockIdx.z;
  int nc = cnt[e];
  int sr = blockIdx.y*64;
  if(sr >= nc) return;
  const int K = FDIM;
  const u16* A  = act   + (size_t)e*CAP*FDIM;
  const u16* Bt = downT + (size_t)e*CDIM*FDIM;
  const int* be = bidx + e*CAP;
  const float* bwe = bw + e*CAP;
  __shared__ u16 As[64][80];
  __shared__ u16 Bs[64][80];
  int tid = threadIdx.x;
  int bc = blockIdx.x*64;
  int w = tid>>6, lane = tid&63, wr = w>>1, wc = w&1, g = lane>>4, cl = lane&15;
  f32x4 zero = {0.f,0.f,0.f,0.f};
  f32x4 acc[2][2];
  acc[0][0]=acc[0][1]=acc[1][0]=acc[1][1]=zero;
  for(int k0=0;k0<K;k0+=64){
    #pragma unroll
    for(int s=0;s<2;s++){
      int cid = tid + s*256;
      int r = cid>>3, c8 = (cid&7)*8;
      *(uint4*)&As[r][c8] = *(const uint4*)(A  + (size_t)(sr+r)*K + k0 + c8);
      *(uint4*)&Bs[r][c8] = *(const uint4*)(Bt + (size_t)(bc+r)*K + k0 + c8);
    }
    __syncthreads();
    #pragma unroll
    for(int kk=0;kk<64;kk+=32){
      bf16x8 af[2], bfr[2];
      #pragma unroll
      for(int m=0;m<2;m++) af[m] = *(const bf16x8*)&As[wr*32 + m*16 + cl][kk + g*8];
      #pragma unroll
      for(int n=0;n<2;n++) bfr[n] = *(const bf16x8*)&Bs[wc*32 + n*16 + cl][kk + g*8];
      #pragma unroll
      for(int m=0;m<2;m++)
        #pragma unroll
        for(int n=0;n<2;n++)
          acc[m][n] = mfma_bf16(af[m], bfr[n], acc[m][n]);
    }
    __syncthreads();
  }
  #pragma unroll
  for(int m=0;m<2;m++)
    #pragma unroll
    for(int n=0;n<2;n++)
      #pragma unroll
      for(int j=0;j<4;j++){
        int slot = sr + wr*32 + m*16 + g*4 + j;
        if(slot < nc){
          int tok = be[slot];
          float wgt = bwe[slot];
          int col = bc + wc*32 + n*16 + cl;
          atomicAdd(out + (size_t)tok*CDIM + col, wgt * acc[m][n][j]);
        }
      }
}

// ------------------------------------ launch ---------------------------------------
extern "C" void kernel_launch(void* const* d_in, const int* in_sizes, int n_in,
                              void* d_out, int out_size, void* d_ws, size_t ws_size,
                              hipStream_t stream)
{
  const float* x     = (const float*)d_in[0];
  const float* cosb  = (const float*)d_in[1];
  const float* sinb  = (const float*)d_in[2];
  const float* ln1w  = (const float*)d_in[3];
  const float* qw    = (const float*)d_in[4];
  const float* kw    = (const float*)d_in[5];
  const float* vw    = (const float*)d_in[6];
  const float* ow    = (const float*)d_in[7];
  const float* qnw   = (const float*)d_in[8];
  const float* knw   = (const float*)d_in[9];
  const float* ln2w  = (const float*)d_in[10];
  const float* gatew = (const float*)d_in[11];
  const float* gupw  = (const float*)d_in[12];
  const float* downw = (const float*)d_in[13];
  float* out = (float*)d_out;

  char* ws = (char*)d_ws;
  size_t off = 0;
  auto alloc = [&](size_t bytes)->char*{
    char* p = ws + off;
    off = (off + bytes + 255) & ~(size_t)255;
    return p;
  };
  u16*   wqkvT = (u16*)  alloc((size_t)6144*2048*2);
  u16*   owT   = (u16*)  alloc((size_t)2048*4096*2);
  u16*   gupT  = (u16*)  alloc((size_t)8*1536*2048*2);
  u16*   downT = (u16*)  alloc((size_t)8*2048*768*2);
  u16*   h1b   = (u16*)  alloc((size_t)2048*2048*2);
  float* qkvf  = (float*)alloc((size_t)2048*6144*4);
  u16*   qb    = (u16*)  alloc((size_t)2*32*1024*128*2);
  u16*   kb    = (u16*)  alloc((size_t)2*8*1024*128*2);
  u16*   vt    = (u16*)  alloc((size_t)2*8*1024*128*2);
  u16*   aob   = (u16*)  alloc((size_t)2048*4096*2);
  float* h2f   = (float*)alloc((size_t)2048*2048*4);
  u16*   h2b   = (u16*)  alloc((size_t)2048*2048*2);
  u16*   actb  = (u16*)  alloc((size_t)8*2048*768*2);
  int*   bidx  = (int*)  alloc((size_t)8*2048*4);
  float* bwgt  = (float*)alloc((size_t)8*2048*4);
  int*   cnt   = (int*)  alloc(64);
  (void)ws_size; (void)in_sizes; (void)n_in; (void)out_size;

  hipMemsetAsync(cnt, 0, 8*sizeof(int), stream);

  // weight transposes/casts
  cast_transpose<<<dim3(128,64,1), 256, 0, stream>>>(qw, wqkvT,                  2048, 4096, 4096, 1, 0, 0);
  cast_transpose<<<dim3(32, 64,1), 256, 0, stream>>>(kw, wqkvT + (size_t)4096*2048, 2048, 1024, 1024, 1, 0, 0);
  cast_transpose<<<dim3(32, 64,1), 256, 0, stream>>>(vw, wqkvT + (size_t)5120*2048, 2048, 1024, 1024, 1, 0, 0);
  cast_transpose<<<dim3(64,128,1), 256, 0, stream>>>(ow, owT,                    4096, 2048, 2048, 1, 0, 0);
  cast_transpose<<<dim3(48, 64,8), 256, 0, stream>>>(gupw, gupT,                 2048, 1536, 1536, 8, 0, (long long)2048*1536);
  cast_transpose<<<dim3(64, 24,8), 256, 0, stream>>>(downw, downT,               768,  2048, 2048, 8, 0, (long long)768*2048);

  // ln1 + cast
  rmsnorm_kernel<<<2048, 256, 0, stream>>>(x, ln1w, h1b, nullptr);
  // qkv = h @ [q|k|v]   (M=2048, N=6144, K=2048)
  gemm128<<<dim3(48,16), 256, 0, stream>>>(h1b, wqkvT, qkvf, nullptr, 2048, 6144, 2048);
  // q/k: per-head rmsnorm + rope -> bf16
  qk_norm_rope<<<dim3(2048,40), 128, 0, stream>>>(qkvf, cosb, sinb, qnw, knw, qb, kb);
  // v -> (b,kv,D,T) bf16
  cast_transpose<<<dim3(4,32,16), 256, 0, stream>>>(qkvf + 5120, vt, 1024, 128, 6144, 8,
                                                    (long long)1024*6144, 128);
  // attention
  attn_kernel<<<dim3(32,8,2), 256, 0, stream>>>(qb, kb, vt, aob);
  // o-proj + residual -> d_out (= x1)   (M=2048, N=2048, K=4096)
  gemm128<<<dim3(16,16), 256, 0, stream>>>(aob, owT, out, x, 2048, 2048, 4096);
  // ln2 (fp32 + bf16)
  rmsnorm_kernel<<<2048, 256, 0, stream>>>(out, ln2w, h2b, h2f);
  // routing
  route_kernel<<<512, 256, 0, stream>>>(h2f, gatew, cnt, bidx, bwgt);
  // experts
  gemm_gateup<<<dim3(12,32,8), 256, 0, stream>>>(h2b, gupT, actb, bidx, cnt);
  gemm_down<<<dim3(32,32,8), 256, 0, stream>>>(actb, downT, out, bidx, bwgt, cnt);
}